// Round 6
// baseline (339.746 us; speedup 1.0000x reference)
//
#include <hip/hip_runtime.h>

// GConv: out = spmm(A0, S) + spmm(A1, S) + bias,  S = x @ W
// N=100000, E=600000, F_IN=F_OUT=128.
// R6: chain walk (latency-serial) split from gather (throughput):
//   build_rec(+hist) -> scan -> compact (thread/row, chains -> CSR) ->
//   pull_csr (wave/row, coalesced metadata + independent gathers).
// R5's pull walked the chain inside the gather kernel: 12-deep dependent
// scattered loads, latency-bound at 135us / 1.9TB/s.

#define FDIM 128
#define SCAN_TILE 2048

typedef __attribute__((ext_vector_type(8))) short short8;
typedef __attribute__((ext_vector_type(4))) float floatx4;

__device__ __forceinline__ unsigned short f32_to_bf16(float f) {
    unsigned int u = __float_as_uint(f);
    unsigned int r = u + 0x7fffu + ((u >> 16) & 1u);   // RNE
    return (unsigned short)(r >> 16);
}
__device__ __forceinline__ float bf16_lo(unsigned int u) {
    return __uint_as_float((u & 0xffffu) << 16);
}
__device__ __forceinline__ float bf16_hi(unsigned int u) {
    return __uint_as_float(u & 0xffff0000u);
}

// ---------------- Wt[n][k] = bf16(W[k][n]) — one-shot ----------------------
__global__ __launch_bounds__(256) void wt_conv(const float* __restrict__ w,
                                               unsigned short* __restrict__ wt) {
    int idx = blockIdx.x * 256 + threadIdx.x;   // 0..16383
    int nn = idx >> 7, k = idx & 127;
    wt[idx] = f32_to_bf16(w[(size_t)k * FDIM + nn]);
}

// ---------------- GEMM: support(bf16) = x @ W via MFMA ---------------------
__global__ __launch_bounds__(256) void gemm_mfma(const float* __restrict__ x,
                                                 const unsigned short* __restrict__ wt,
                                                 unsigned short* __restrict__ support,
                                                 int n) {
    __shared__ __align__(16) short As[64][136];
    __shared__ __align__(16) short Bs[128][136];
    const int tid = threadIdx.x;
    const int m0 = blockIdx.x * 64;

    #pragma unroll
    for (int i = 0; i < 8; ++i) {
        int idx = tid + i * 256;
        int r = idx >> 5, c4 = idx & 31;
        float4 v = make_float4(0.f, 0.f, 0.f, 0.f);
        if (m0 + r < n) v = *(const float4*)(x + (size_t)(m0 + r) * FDIM + c4 * 4);
        short4 s;
        s.x = (short)f32_to_bf16(v.x); s.y = (short)f32_to_bf16(v.y);
        s.z = (short)f32_to_bf16(v.z); s.w = (short)f32_to_bf16(v.w);
        *(short4*)&As[r][c4 * 4] = s;
    }
    #pragma unroll
    for (int i = 0; i < 8; ++i) {
        int idx = tid + i * 256;
        int r = idx >> 4, c8 = idx & 15;
        short8 v = *(const short8*)(wt + (size_t)r * FDIM + c8 * 8);
        *(short8*)&Bs[r][c8 * 8] = v;
    }
    __syncthreads();

    const int wv = tid >> 6;
    const int lane = tid & 63;
    const int quad = lane >> 4;
    const int lr = lane & 15;

    floatx4 acc[8];
    #pragma unroll
    for (int nt = 0; nt < 8; ++nt) acc[nt] = (floatx4)0.f;

    #pragma unroll
    for (int ks = 0; ks < 4; ++ks) {
        short8 a = *(const short8*)&As[wv * 16 + lr][ks * 32 + quad * 8];
        #pragma unroll
        for (int nt = 0; nt < 8; ++nt) {
            short8 b = *(const short8*)&Bs[nt * 16 + lr][ks * 32 + quad * 8];
            acc[nt] = __builtin_amdgcn_mfma_f32_16x16x32_bf16(a, b, acc[nt], 0, 0, 0);
        }
    }

    #pragma unroll
    for (int i = 0; i < 4; ++i) {
        int row = m0 + wv * 16 + quad * 4 + i;
        if (row < n) {
            #pragma unroll
            for (int nt = 0; nt < 8; ++nt)
                support[(size_t)row * FDIM + nt * 16 + lr] = f32_to_bf16(acc[nt][i]);
        }
    }
}

// ---------------- build: chains + histogram in one pass --------------------
__global__ __launch_bounds__(256) void build_rec(const int* __restrict__ rows0,
                                                 const int* __restrict__ cols0,
                                                 const float* __restrict__ vals0,
                                                 const int* __restrict__ rows1,
                                                 const int* __restrict__ cols1,
                                                 const float* __restrict__ vals1,
                                                 int* __restrict__ head,
                                                 int* __restrict__ counts,
                                                 int4* __restrict__ rec, int E) {
    int gid = blockIdx.x * 256 + threadIdx.x;
    if (gid >= 2 * E) return;
    int r, c; float v;
    if (gid < E) { r = rows0[gid]; c = cols0[gid]; v = vals0[gid]; }
    else         { int e = gid - E; r = rows1[e]; c = cols1[e]; v = vals1[e]; }
    int old = atomicExch(&head[r], gid);
    atomicAdd(&counts[r], 1);
    rec[gid] = make_int4(old, c, __float_as_int(v), 0);
}

// ---------------- 3-phase device-wide exclusive scan -----------------------
__global__ __launch_bounds__(256) void scan_p1(const int* __restrict__ counts,
                                               int* __restrict__ blockSums, int n) {
    __shared__ int sdata[256];
    const int t = threadIdx.x;
    const int base = blockIdx.x * SCAN_TILE + t * 8;
    int sum = 0;
    #pragma unroll
    for (int i = 0; i < 8; ++i) {
        int idx = base + i;
        if (idx < n) sum += counts[idx];
    }
    sdata[t] = sum;
    __syncthreads();
    for (int d = 128; d > 0; d >>= 1) {
        if (t < d) sdata[t] += sdata[t + d];
        __syncthreads();
    }
    if (t == 0) blockSums[blockIdx.x] = sdata[0];
}

__global__ __launch_bounds__(512) void scan_p2(int* __restrict__ blockSums,
                                               int* __restrict__ rowptr,
                                               int nb, int n) {
    __shared__ int sdata[512];
    const int t = threadIdx.x;
    int v = (t < nb) ? blockSums[t] : 0;
    sdata[t] = v;
    __syncthreads();
    for (int d = 1; d < 512; d <<= 1) {
        int u = (t >= d) ? sdata[t - d] : 0;
        __syncthreads();
        sdata[t] += u;
        __syncthreads();
    }
    if (t < nb) blockSums[t] = sdata[t] - v;
    if (t == 511) rowptr[n] = sdata[511];
}

__global__ __launch_bounds__(256) void scan_p3(const int* __restrict__ counts,
                                               const int* __restrict__ blockSums,
                                               int* __restrict__ rowptr, int n) {
    __shared__ int sdata[256];
    const int t = threadIdx.x;
    const int base = blockIdx.x * SCAN_TILE + t * 8;
    int loc[8];
    int sum = 0;
    #pragma unroll
    for (int i = 0; i < 8; ++i) {
        int idx = base + i;
        int c = (idx < n) ? counts[idx] : 0;
        loc[i] = sum;
        sum += c;
    }
    sdata[t] = sum;
    __syncthreads();
    const int mine = sum;
    for (int d = 1; d < 256; d <<= 1) {
        int u = (t >= d) ? sdata[t - d] : 0;
        __syncthreads();
        sdata[t] += u;
        __syncthreads();
    }
    const int off = sdata[t] - mine + blockSums[blockIdx.x];
    #pragma unroll
    for (int i = 0; i < 8; ++i) {
        int idx = base + i;
        if (idx < n) rowptr[idx] = off + loc[i];
    }
}

// ---------------- compact: thread/row, chain -> contiguous CSR segment -----
__global__ __launch_bounds__(256) void compact(const int* __restrict__ head,
                                               const int4* __restrict__ rec,
                                               const int* __restrict__ rowptr,
                                               int2* __restrict__ csr, int n) {
    int r = blockIdx.x * 256 + threadIdx.x;
    if (r >= n) return;
    int pos = rowptr[r];
    int e = head[r];
    while (e >= 0) {
        int4 rc = rec[e];
        csr[pos++] = make_int2(rc.y, rc.z);
        e = rc.x;
    }
}

// ---------------- pull: wave/row, shfl-broadcast metadata, indep gathers ---
__global__ __launch_bounds__(256) void pull_csr(const unsigned short* __restrict__ support,
                                                const int* __restrict__ rowptr,
                                                const int2* __restrict__ csr,
                                                const float* __restrict__ bias,
                                                float* __restrict__ out, int n) {
    int wid = (blockIdx.x * 256 + threadIdx.x) >> 6;
    int lane = threadIdx.x & 63;
    if (wid >= n) return;
    int s = rowptr[wid];
    int e = rowptr[wid + 1];
    float ax = 0.f, ay = 0.f;
    for (int base = s; base < e; base += 64) {
        int len = min(64, e - base);
        int2 me = make_int2(0, 0);
        if (lane < len) me = csr[base + lane];
        int j = 0;
        for (; j + 1 < len; j += 2) {
            int   c0 = __shfl(me.x, j);
            int   c1 = __shfl(me.x, j + 1);
            float v0 = __int_as_float(__shfl(me.y, j));
            float v1 = __int_as_float(__shfl(me.y, j + 1));
            unsigned int u0 = *(const unsigned int*)(support + (size_t)c0 * FDIM + lane * 2);
            unsigned int u1 = *(const unsigned int*)(support + (size_t)c1 * FDIM + lane * 2);
            ax += v0 * bf16_lo(u0) + v1 * bf16_lo(u1);
            ay += v0 * bf16_hi(u0) + v1 * bf16_hi(u1);
        }
        if (j < len) {
            int   c = __shfl(me.x, j);
            float v = __int_as_float(__shfl(me.y, j));
            unsigned int u = *(const unsigned int*)(support + (size_t)c * FDIM + lane * 2);
            ax += v * bf16_lo(u);
            ay += v * bf16_hi(u);
        }
    }
    float2 b = *(const float2*)(bias + lane * 2);
    *(float2*)(out + (size_t)wid * FDIM + lane * 2) = make_float2(ax + b.x, ay + b.y);
}

// ---------------- fallback: atomic scatter ---------------------------------
__global__ __launch_bounds__(256) void init_bias(const float* __restrict__ bias,
                                                 float* __restrict__ out, int n) {
    int idx = blockIdx.x * 256 + threadIdx.x;
    int total = n * (FDIM / 4);
    if (idx < total) {
        int j = (idx & (FDIM / 4 - 1)) * 4;
        float4 b = *(const float4*)(bias + j);
        *(float4*)(out + (size_t)idx * 4) = b;
    }
}

__global__ __launch_bounds__(256) void scatter_bf16(
    const unsigned short* __restrict__ support,
    const int* __restrict__ rows0, const int* __restrict__ cols0, const float* __restrict__ vals0,
    const int* __restrict__ rows1, const int* __restrict__ cols1, const float* __restrict__ vals1,
    float* __restrict__ out, int E) {
    int gid = blockIdx.x * 256 + threadIdx.x;
    int lane = gid & 63;
    int eg = gid >> 6;
    if (eg >= 2 * E) return;
    int r, c; float v;
    if (eg < E) { r = rows0[eg]; c = cols0[eg]; v = vals0[eg]; }
    else        { int e = eg - E; r = rows1[e]; c = cols1[e]; v = vals1[e]; }
    unsigned int u = *(const unsigned int*)(support + (size_t)c * FDIM + lane * 2);
    float* op = out + (size_t)r * FDIM + lane * 2;
    atomicAdd(op,     bf16_lo(u) * v);
    atomicAdd(op + 1, bf16_hi(u) * v);
}

static inline size_t align256(size_t v) { return (v + 255) & ~(size_t)255; }

extern "C" void kernel_launch(void* const* d_in, const int* in_sizes, int n_in,
                              void* d_out, int out_size, void* d_ws, size_t ws_size,
                              hipStream_t stream) {
    const float* x     = (const float*)d_in[0];
    const float* w     = (const float*)d_in[1];
    const float* bias  = (const float*)d_in[2];
    const float* vals0 = (const float*)d_in[3];
    const float* vals1 = (const float*)d_in[4];
    const int*   rows0 = (const int*)d_in[5];
    const int*   cols0 = (const int*)d_in[6];
    const int*   rows1 = (const int*)d_in[7];
    const int*   cols1 = (const int*)d_in[8];
    const int n = in_sizes[0] / FDIM;
    const int E = in_sizes[3];
    float* out = (float*)d_out;

    const int nScanBlocks = (n + SCAN_TILE - 1) / SCAN_TILE;

    size_t off = 0;
    unsigned short* support = (unsigned short*)((char*)d_ws + off);
    off = align256(off + (size_t)n * FDIM * 2);
    unsigned short* wt = (unsigned short*)((char*)d_ws + off);
    off = align256(off + (size_t)FDIM * FDIM * 2);
    int*  head      = (int*)((char*)d_ws + off);  off = align256(off + (size_t)n * 4);
    int*  counts    = (int*)((char*)d_ws + off);  off = align256(off + (size_t)n * 4);
    int*  rowptr    = (int*)((char*)d_ws + off);  off = align256(off + (size_t)(n + 1) * 4);
    int*  blockSums = (int*)((char*)d_ws + off);  off = align256(off + (size_t)nScanBlocks * 4);
    int4* rec       = (int4*)((char*)d_ws + off); off = align256(off + (size_t)2 * E * 16);
    int2* csr       = (int2*)((char*)d_ws + off); off = align256(off + (size_t)2 * E * 8);

    wt_conv<<<(FDIM * FDIM) / 256, 256, 0, stream>>>(w, wt);
    gemm_mfma<<<(n + 63) / 64, 256, 0, stream>>>(x, wt, support, n);

    if (off <= ws_size && nScanBlocks <= 512) {
        hipMemsetAsync(head, 0xFF, (size_t)n * 4, stream);
        hipMemsetAsync(counts, 0, (size_t)n * 4, stream);
        int eb = (2 * E + 255) / 256;
        build_rec<<<eb, 256, 0, stream>>>(rows0, cols0, vals0, rows1, cols1, vals1,
                                          head, counts, rec, E);
        scan_p1<<<nScanBlocks, 256, 0, stream>>>(counts, blockSums, n);
        scan_p2<<<1, 512, 0, stream>>>(blockSums, rowptr, nScanBlocks, n);
        scan_p3<<<nScanBlocks, 256, 0, stream>>>(counts, blockSums, rowptr, n);
        compact<<<(n + 255) / 256, 256, 0, stream>>>(head, rec, rowptr, csr, n);
        pull_csr<<<(n + 3) / 4, 256, 0, stream>>>(support, rowptr, csr, bias, out, n);
    } else {
        int total4 = n * (FDIM / 4);
        init_bias<<<(total4 + 255) / 256, 256, 0, stream>>>(bias, out, n);
        long long tthreads = 2LL * E * 64;
        int blocks = (int)((tthreads + 255) / 256);
        scatter_bf16<<<blocks, 256, 0, stream>>>(support, rows0, cols0, vals0,
                                                 rows1, cols1, vals1, out, E);
    }
}